// Round 1
// baseline (118.860 us; speedup 1.0000x reference)
//
#include <hip/hip_runtime.h>

// TwoAgentGNN: B=1M two-node graphs, N=2B nodes, IN_D=4, HID_D=16, OUT_D=4.
// Static topology: partner(i) = i^1, so edge_index (d_in[1]) is never read.
//
// Pair-symmetry factorization (halves FMA count):
//   s = a+c, d = a-c, W+ = (Wr+We)/2, W- = (Wr-We)/2
//   a*Wr + c*We = s*W+ + d*W-   ;   c*Wr + a*We = s*W+ - d*W-
// Applied in both layers (relu only breaks symmetry between u and v, not the
// shared-u structure).
//
// Combined weights staged in LDS (transposed for float4 broadcast reads).

__global__ void __launch_bounds__(256) gnn2_kernel(
    const float* __restrict__ x,
    const float* __restrict__ Wr1, const float* __restrict__ We1,
    const float* __restrict__ b1,
    const float* __restrict__ Wr2, const float* __restrict__ We2,
    const float* __restrict__ b2,
    float* __restrict__ out, int nGraphs)
{
    // Wh1/Wm1 stored transposed [k][d] (k=0..15, d=0..3)  -> float4 per k
    // Wh2/Wm2 stored transposed [j][k] (j=0..3,  k=0..15) -> 4x float4 per j
    __shared__ float4 sWh1[16], sWm1[16], sWh2[16], sWm2[16];
    __shared__ float  sB1[16], sB2[4];

    const int tid = threadIdx.x;
    if (tid < 64) {
        const int k = tid >> 2, d = tid & 3;
        const float r = Wr1[d * 16 + k], e = We1[d * 16 + k];
        ((float*)sWh1)[tid] = 0.5f * (r + e);
        ((float*)sWm1)[tid] = 0.5f * (r - e);
    } else if (tid < 128) {
        const int t = tid - 64;
        const int j = t >> 4, k = t & 15;
        const float r = Wr2[k * 4 + j], e = We2[k * 4 + j];
        ((float*)sWh2)[t] = 0.5f * (r + e);
        ((float*)sWm2)[t] = 0.5f * (r - e);
    } else if (tid < 144) {
        sB1[tid - 128] = b1[tid - 128];
    } else if (tid < 148) {
        sB2[tid - 144] = b2[tid - 144];
    }
    __syncthreads();

    const float4* __restrict__ xv = (const float4*)x;
    float4* __restrict__ ov = (float4*)out;

    int g = blockIdx.x * blockDim.x + threadIdx.x;
    const int stride = gridDim.x * blockDim.x;
    for (; g < nGraphs; g += stride) {
        const float4 a = xv[2 * g];
        const float4 c = xv[2 * g + 1];

        float4 s, d;
        s.x = a.x + c.x; s.y = a.y + c.y; s.z = a.z + c.z; s.w = a.w + c.w;
        d.x = a.x - c.x; d.y = a.y - c.y; d.z = a.z - c.z; d.w = a.w - c.w;

        // ---- layer 1: u = s*W+ , v = d*W- ; h0 = relu(u+v+b1), h1 = relu(u-v+b1)
        float s2[16], d2[16];
        #pragma unroll
        for (int k = 0; k < 16; ++k) {
            const float4 wh = sWh1[k];
            const float4 wm = sWm1[k];
            const float u = fmaf(s.x, wh.x, fmaf(s.y, wh.y, fmaf(s.z, wh.z, s.w * wh.w)));
            const float v = fmaf(d.x, wm.x, fmaf(d.y, wm.y, fmaf(d.z, wm.z, d.w * wm.w)));
            const float bb = sB1[k];
            const float h0 = fmaxf(u + v + bb, 0.0f);
            const float h1 = fmaxf(u - v + bb, 0.0f);
            s2[k] = h0 + h1;
            d2[k] = h0 - h1;
        }

        // ---- layer 2: u2 = s2*W+ , v2 = d2*W- ; out0 = u2+v2+b2, out1 = u2-v2+b2
        float o0[4], o1[4];
        #pragma unroll
        for (int j = 0; j < 4; ++j) {
            float au = 0.0f, av = 0.0f;
            #pragma unroll
            for (int q = 0; q < 4; ++q) {
                const float4 wh = sWh2[j * 4 + q];
                const float4 wm = sWm2[j * 4 + q];
                au = fmaf(s2[4 * q + 0], wh.x, au);
                au = fmaf(s2[4 * q + 1], wh.y, au);
                au = fmaf(s2[4 * q + 2], wh.z, au);
                au = fmaf(s2[4 * q + 3], wh.w, au);
                av = fmaf(d2[4 * q + 0], wm.x, av);
                av = fmaf(d2[4 * q + 1], wm.y, av);
                av = fmaf(d2[4 * q + 2], wm.z, av);
                av = fmaf(d2[4 * q + 3], wm.w, av);
            }
            const float bb = sB2[j];
            o0[j] = au + av + bb;
            o1[j] = au - av + bb;
        }

        ov[2 * g]     = make_float4(o0[0], o0[1], o0[2], o0[3]);
        ov[2 * g + 1] = make_float4(o1[0], o1[1], o1[2], o1[3]);
    }
}

extern "C" void kernel_launch(void* const* d_in, const int* in_sizes, int n_in,
                              void* d_out, int out_size, void* d_ws, size_t ws_size,
                              hipStream_t stream) {
    const float* x   = (const float*)d_in[0];
    // d_in[1] = edge_index — topology is static (partner = i^1), never read.
    const float* Wr1 = (const float*)d_in[2];
    const float* We1 = (const float*)d_in[3];
    const float* b1  = (const float*)d_in[4];
    const float* Wr2 = (const float*)d_in[5];
    const float* We2 = (const float*)d_in[6];
    const float* b2  = (const float*)d_in[7];
    float* out = (float*)d_out;

    const int nGraphs = in_sizes[0] / 8;   // N*IN_D / (2*4) = B

    const int block = 256;
    const int grid = 2048;                 // grid-stride, ~1.9 graphs/thread
    gnn2_kernel<<<grid, block, 0, stream>>>(x, Wr1, We1, b1, Wr2, We2, b2,
                                            out, nGraphs);
}

// Round 2
// 110.364 us; speedup vs baseline: 1.0770x; 1.0770x over previous
//
#include <hip/hip_runtime.h>

// TwoAgentGNN: B=1M two-node graphs, N=2B nodes, IN_D=4, HID_D=16, OUT_D=4.
// Static topology: partner(i) = i^1 -> edge_index (d_in[1]) never read.
//
// Pair-symmetry factorization (halves FMAs):
//   s = a+c, d = a-c, W+ = (Wr+We)/2, W- = (Wr-We)/2
//   a*Wr + c*We = s*W+ + d*W-  ;  c*Wr + a*We = s*W+ - d*W-
//
// Round-2 changes vs round-1:
//  * 2 graphs per thread -> every LDS weight read (broadcast ds_read_b128)
//    is shared by 2 graphs (69 -> 34.5 reads/graph) and the two independent
//    FMA chains give 2x ILP on the dependent dot-product latency.
//  * exact one-pass grid (no grid-stride remainder imbalance)
//  * nontemporal stores for the write-only output stream
//  * ext_vector float4 for clean elementwise codegen

typedef float f4 __attribute__((ext_vector_type(4)));

__global__ void __launch_bounds__(256) gnn2_kernel(
    const f4* __restrict__ xv,
    const float* __restrict__ Wr1, const float* __restrict__ We1,
    const float* __restrict__ b1,
    const float* __restrict__ Wr2, const float* __restrict__ We2,
    const float* __restrict__ b2,
    f4* __restrict__ ov, int nPairs)
{
    // Wh1/Wm1 transposed [k][d] (k=0..15) -> one f4 per k
    // Wh2/Wm2 transposed [j][q] (j=0..3, q=0..3 covering k=4q..4q+3)
    __shared__ f4 sWh1[16], sWm1[16], sWh2[16], sWm2[16];
    __shared__ float sB1[16], sB2[4];

    const int tid = threadIdx.x;
    if (tid < 64) {
        const int k = tid >> 2, d = tid & 3;
        const float r = Wr1[d * 16 + k], e = We1[d * 16 + k];
        ((float*)sWh1)[tid] = 0.5f * (r + e);
        ((float*)sWm1)[tid] = 0.5f * (r - e);
    } else if (tid < 128) {
        const int t = tid - 64;
        const int j = t >> 4, k = t & 15;
        const float r = Wr2[k * 4 + j], e = We2[k * 4 + j];
        ((float*)sWh2)[t] = 0.5f * (r + e);
        ((float*)sWm2)[t] = 0.5f * (r - e);
    } else if (tid < 144) {
        sB1[tid - 128] = b1[tid - 128];
    } else if (tid < 148) {
        sB2[tid - 144] = b2[tid - 144];
    }
    __syncthreads();

    const int p = blockIdx.x * blockDim.x + tid;   // pair of graphs
    if (p >= nPairs) return;

    // 64 contiguous bytes per lane; wave covers 4 KB contiguous
    const f4 a0 = xv[4 * p + 0];
    const f4 c0 = xv[4 * p + 1];
    const f4 a1 = xv[4 * p + 2];
    const f4 c1 = xv[4 * p + 3];

    const f4 s0 = a0 + c0, e0 = a0 - c0;
    const f4 s1 = a1 + c1, e1 = a1 - c1;

    // ---- layer 1 (both graphs share each weight read) ----
    float sa[16], da[16], sb[16], db[16];
    #pragma unroll
    for (int k = 0; k < 16; ++k) {
        const f4 wh = sWh1[k];
        const f4 wm = sWm1[k];
        const float bb = sB1[k];

        const float u0 = fmaf(s0.x, wh.x, fmaf(s0.y, wh.y, fmaf(s0.z, wh.z, s0.w * wh.w)));
        const float v0 = fmaf(e0.x, wm.x, fmaf(e0.y, wm.y, fmaf(e0.z, wm.z, e0.w * wm.w)));
        const float u1 = fmaf(s1.x, wh.x, fmaf(s1.y, wh.y, fmaf(s1.z, wh.z, s1.w * wh.w)));
        const float v1 = fmaf(e1.x, wm.x, fmaf(e1.y, wm.y, fmaf(e1.z, wm.z, e1.w * wm.w)));

        const float h00 = fmaxf(u0 + v0 + bb, 0.0f);
        const float h01 = fmaxf(u0 - v0 + bb, 0.0f);
        const float h10 = fmaxf(u1 + v1 + bb, 0.0f);
        const float h11 = fmaxf(u1 - v1 + bb, 0.0f);

        sa[k] = h00 + h01;  da[k] = h00 - h01;
        sb[k] = h10 + h11;  db[k] = h10 - h11;
    }

    // ---- layer 2 (weights shared across both graphs) ----
    f4 o00, o01, o10, o11;
    float* p00 = (float*)&o00; float* p01 = (float*)&o01;
    float* p10 = (float*)&o10; float* p11 = (float*)&o11;
    #pragma unroll
    for (int j = 0; j < 4; ++j) {
        float au0 = 0.0f, av0 = 0.0f, au1 = 0.0f, av1 = 0.0f;
        #pragma unroll
        for (int q = 0; q < 4; ++q) {
            const f4 wh = sWh2[j * 4 + q];
            const f4 wm = sWm2[j * 4 + q];
            au0 = fmaf(sa[4*q+0], wh.x, au0); au0 = fmaf(sa[4*q+1], wh.y, au0);
            au0 = fmaf(sa[4*q+2], wh.z, au0); au0 = fmaf(sa[4*q+3], wh.w, au0);
            av0 = fmaf(da[4*q+0], wm.x, av0); av0 = fmaf(da[4*q+1], wm.y, av0);
            av0 = fmaf(da[4*q+2], wm.z, av0); av0 = fmaf(da[4*q+3], wm.w, av0);
            au1 = fmaf(sb[4*q+0], wh.x, au1); au1 = fmaf(sb[4*q+1], wh.y, au1);
            au1 = fmaf(sb[4*q+2], wh.z, au1); au1 = fmaf(sb[4*q+3], wh.w, au1);
            av1 = fmaf(db[4*q+0], wm.x, av1); av1 = fmaf(db[4*q+1], wm.y, av1);
            av1 = fmaf(db[4*q+2], wm.z, av1); av1 = fmaf(db[4*q+3], wm.w, av1);
        }
        const float bb = sB2[j];
        p00[j] = au0 + av0 + bb;
        p01[j] = au0 - av0 + bb;
        p10[j] = au1 + av1 + bb;
        p11[j] = au1 - av1 + bb;
    }

    // write-only stream -> nontemporal stores
    __builtin_nontemporal_store(o00, &ov[4 * p + 0]);
    __builtin_nontemporal_store(o01, &ov[4 * p + 1]);
    __builtin_nontemporal_store(o10, &ov[4 * p + 2]);
    __builtin_nontemporal_store(o11, &ov[4 * p + 3]);
}

extern "C" void kernel_launch(void* const* d_in, const int* in_sizes, int n_in,
                              void* d_out, int out_size, void* d_ws, size_t ws_size,
                              hipStream_t stream) {
    const float* x   = (const float*)d_in[0];
    // d_in[1] = edge_index — static topology, never read.
    const float* Wr1 = (const float*)d_in[2];
    const float* We1 = (const float*)d_in[3];
    const float* b1  = (const float*)d_in[4];
    const float* Wr2 = (const float*)d_in[5];
    const float* We2 = (const float*)d_in[6];
    const float* b2  = (const float*)d_in[7];

    const int nGraphs = in_sizes[0] / 8;   // N*IN_D / (2*4) = B
    const int nPairs  = nGraphs / 2;       // B even (1M) — 2 graphs/thread

    const int block = 256;
    const int grid  = (nPairs + block - 1) / block;   // 1954 blocks, one pass
    gnn2_kernel<<<grid, block, 0, stream>>>((const f4*)x, Wr1, We1, b1,
                                            Wr2, We2, b2, (f4*)d_out, nPairs);
}

// Round 3
// 104.493 us; speedup vs baseline: 1.1375x; 1.0562x over previous
//
#include <hip/hip_runtime.h>

// TwoAgentGNN: B=1M two-node graphs, N=2B nodes, IN_D=4, HID_D=16, OUT_D=4.
// Static topology: partner(i) = i^1 -> edge_index (d_in[1]) never read.
//
// Round-3 theory: r2 was LDS-issue-bound (~84 ds_read/wave on the single
// per-CU LDS pipe ~= 11 us device-wide, vs 10.2 us HBM floor and only
// ~5 us of VALU). Fix: NO LDS at all. Weights are wave-uniform, so read
// them with literal indices from the const __restrict__ global pointers ->
// uniformity analysis turns them into s_load -> SGPRs (scalar pipe, free
// v_fma operand). This requires the DIRECT form (a*Wr + c*We per node,
// no W+/W- combine, since combining needs FP math that can't run on the
// scalar unit and a setup kernel would cost ~2 us of graph launch overhead).
// VALU rises to ~580 ops/graph ~= 7.6 us device-wide -- still under the
// 10.2 us memory floor, so it hides behind the streaming loads/stores.
//
// Per thread: 1 graph = 2 nodes. 32B contiguous load, 32B contiguous
// nontemporal store. ~60 VGPR -> 8 waves/SIMD occupancy.

typedef float f4 __attribute__((ext_vector_type(4)));

__global__ void __launch_bounds__(256) gnn2_kernel(
    const f4* __restrict__ xv,
    const float* __restrict__ Wr1, const float* __restrict__ We1,
    const float* __restrict__ b1,
    const float* __restrict__ Wr2, const float* __restrict__ We2,
    const float* __restrict__ b2,
    f4* __restrict__ ov, int nGraphs)
{
    const int g = blockIdx.x * blockDim.x + threadIdx.x;
    if (g >= nGraphs) return;

    const f4 a = xv[2 * g];
    const f4 c = xv[2 * g + 1];

    // ---- layer 1: h0 = relu(a*Wr1 + c*We1 + b1), h1 = relu(c*Wr1 + a*We1 + b1)
    // Wr1/We1 are [IN_D=4][HID_D=16] row-major; all weight/bias reads are
    // wave-uniform (literal indices) -> SMEM s_load, zero vector-memory cost.
    float h0[16], h1[16];
#pragma unroll
    for (int k = 0; k < 16; ++k) {
        const float wr_0 = Wr1[0 * 16 + k];
        const float wr_1 = Wr1[1 * 16 + k];
        const float wr_2 = Wr1[2 * 16 + k];
        const float wr_3 = Wr1[3 * 16 + k];
        const float we_0 = We1[0 * 16 + k];
        const float we_1 = We1[1 * 16 + k];
        const float we_2 = We1[2 * 16 + k];
        const float we_3 = We1[3 * 16 + k];
        const float bb = b1[k];

        float t0 = bb;                       // node0: a*Wr + c*We
        t0 = fmaf(a.x, wr_0, t0);
        t0 = fmaf(a.y, wr_1, t0);
        t0 = fmaf(a.z, wr_2, t0);
        t0 = fmaf(a.w, wr_3, t0);
        t0 = fmaf(c.x, we_0, t0);
        t0 = fmaf(c.y, we_1, t0);
        t0 = fmaf(c.z, we_2, t0);
        t0 = fmaf(c.w, we_3, t0);

        float t1 = bb;                       // node1: c*Wr + a*We
        t1 = fmaf(c.x, wr_0, t1);
        t1 = fmaf(c.y, wr_1, t1);
        t1 = fmaf(c.z, wr_2, t1);
        t1 = fmaf(c.w, wr_3, t1);
        t1 = fmaf(a.x, we_0, t1);
        t1 = fmaf(a.y, we_1, t1);
        t1 = fmaf(a.z, we_2, t1);
        t1 = fmaf(a.w, we_3, t1);

        h0[k] = fmaxf(t0, 0.0f);
        h1[k] = fmaxf(t1, 0.0f);
    }

    // ---- layer 2: out0 = h0*Wr2 + h1*We2 + b2, out1 = h1*Wr2 + h0*We2 + b2
    // Wr2/We2 are [HID_D=16][OUT_D=4] row-major.
    f4 o0, o1;
#pragma unroll
    for (int j = 0; j < 4; ++j) {
        const float bb = b2[j];
        float s0 = bb, s1 = bb;
#pragma unroll
        for (int k = 0; k < 16; ++k) {
            const float wr = Wr2[k * 4 + j];
            const float we = We2[k * 4 + j];
            s0 = fmaf(h0[k], wr, s0);
            s0 = fmaf(h1[k], we, s0);
            s1 = fmaf(h1[k], wr, s1);
            s1 = fmaf(h0[k], we, s1);
        }
        o0[j] = s0;
        o1[j] = s1;
    }

    // write-only stream -> nontemporal stores (32B contiguous per thread)
    __builtin_nontemporal_store(o0, &ov[2 * g]);
    __builtin_nontemporal_store(o1, &ov[2 * g + 1]);
}

extern "C" void kernel_launch(void* const* d_in, const int* in_sizes, int n_in,
                              void* d_out, int out_size, void* d_ws, size_t ws_size,
                              hipStream_t stream) {
    const float* x   = (const float*)d_in[0];
    // d_in[1] = edge_index — static topology, never read.
    const float* Wr1 = (const float*)d_in[2];
    const float* We1 = (const float*)d_in[3];
    const float* b1  = (const float*)d_in[4];
    const float* Wr2 = (const float*)d_in[5];
    const float* We2 = (const float*)d_in[6];
    const float* b2  = (const float*)d_in[7];

    const int nGraphs = in_sizes[0] / 8;   // N*IN_D / (2*4) = B

    const int block = 256;
    const int grid  = (nGraphs + block - 1) / block;   // 3907 blocks
    gnn2_kernel<<<grid, block, 0, stream>>>((const f4*)x, Wr1, We1, b1,
                                            Wr2, We2, b2, (f4*)d_out, nGraphs);
}

// Round 4
// 103.376 us; speedup vs baseline: 1.1498x; 1.0108x over previous
//
#include <hip/hip_runtime.h>

// TwoAgentGNN: B=1M two-node graphs, N=2B nodes, IN_D=4, HID_D=16, OUT_D=4.
// Static topology: partner(i) = i^1 -> edge_index (d_in[1]) never read.
//
// Round-4 theory: r3 removed LDS (weights via s_load -> SGPR) and gained
// 5.9 us -- more than the pure-HBM model allowed, implying reads are
// L3-resident (harness d_in restore warms Infinity Cache) and the kernel is
// now VALU-bound (~580 lane-ops/graph ~= 7.4 us device-wide). Fix: packed
// FP32 math. v_pk_fma_f32 (VOP3P, gfx90a+) does 2 FP32 FMAs/instr.
// Restructure as float2 over channel pairs; __builtin_elementwise_fma on
// float2 lowers to llvm.fma.v2f32 -> V_PK_FMA_F32. Weight pairs are
// memory-contiguous -> uniform s_load_dwordx2 (scalar pipe, unchanged).
// Instr count ~560 -> ~300/graph -> VALU ~4 us, under the memory floor.
// Worst case (no packing): identical FMA count to r3, zero regression.

typedef float f4 __attribute__((ext_vector_type(4)));
typedef float f2 __attribute__((ext_vector_type(2)));

static __device__ __forceinline__ f2 bc(float v) { return (f2){v, v}; }

__global__ void __launch_bounds__(256) gnn2_kernel(
    const f4* __restrict__ xv,
    const float* __restrict__ Wr1, const float* __restrict__ We1,
    const float* __restrict__ b1,
    const float* __restrict__ Wr2, const float* __restrict__ We2,
    const float* __restrict__ b2,
    f4* __restrict__ ov, int nGraphs)
{
    const int g = blockIdx.x * blockDim.x + threadIdx.x;
    if (g >= nGraphs) return;

    const f4 a = xv[2 * g];
    const f4 c = xv[2 * g + 1];

    // ---- layer 1: channels k processed in packed pairs (2kk, 2kk+1) ----
    // h0 = relu(a*Wr1 + c*We1 + b1), h1 = relu(c*Wr1 + a*We1 + b1)
    // Wr1/We1: [IN_D=4][HID_D=16] row-major -> k-pairs contiguous (8B aligned).
    f2 h0[8], h1[8];
    const f2 zero2 = (f2){0.0f, 0.0f};
#pragma unroll
    for (int kk = 0; kk < 8; ++kk) {
        const f2 wr0 = *(const f2*)&Wr1[0 * 16 + 2 * kk];
        const f2 wr1 = *(const f2*)&Wr1[1 * 16 + 2 * kk];
        const f2 wr2 = *(const f2*)&Wr1[2 * 16 + 2 * kk];
        const f2 wr3 = *(const f2*)&Wr1[3 * 16 + 2 * kk];
        const f2 we0 = *(const f2*)&We1[0 * 16 + 2 * kk];
        const f2 we1 = *(const f2*)&We1[1 * 16 + 2 * kk];
        const f2 we2 = *(const f2*)&We1[2 * 16 + 2 * kk];
        const f2 we3 = *(const f2*)&We1[3 * 16 + 2 * kk];
        const f2 bb  = *(const f2*)&b1[2 * kk];

        f2 t0 = bb;                          // node0: a*Wr + c*We
        t0 = __builtin_elementwise_fma(bc(a.x), wr0, t0);
        t0 = __builtin_elementwise_fma(bc(a.y), wr1, t0);
        t0 = __builtin_elementwise_fma(bc(a.z), wr2, t0);
        t0 = __builtin_elementwise_fma(bc(a.w), wr3, t0);
        t0 = __builtin_elementwise_fma(bc(c.x), we0, t0);
        t0 = __builtin_elementwise_fma(bc(c.y), we1, t0);
        t0 = __builtin_elementwise_fma(bc(c.z), we2, t0);
        t0 = __builtin_elementwise_fma(bc(c.w), we3, t0);

        f2 t1 = bb;                          // node1: c*Wr + a*We
        t1 = __builtin_elementwise_fma(bc(c.x), wr0, t1);
        t1 = __builtin_elementwise_fma(bc(c.y), wr1, t1);
        t1 = __builtin_elementwise_fma(bc(c.z), wr2, t1);
        t1 = __builtin_elementwise_fma(bc(c.w), wr3, t1);
        t1 = __builtin_elementwise_fma(bc(a.x), we0, t1);
        t1 = __builtin_elementwise_fma(bc(a.y), we1, t1);
        t1 = __builtin_elementwise_fma(bc(a.z), we2, t1);
        t1 = __builtin_elementwise_fma(bc(a.w), we3, t1);

        h0[kk] = __builtin_elementwise_max(t0, zero2);
        h1[kk] = __builtin_elementwise_max(t1, zero2);
    }
    const float* h0s = (const float*)h0;   // unrolled const indices -> stays in VGPRs
    const float* h1s = (const float*)h1;

    // ---- layer 2: outputs j in packed pairs (2jj, 2jj+1) ----
    // out0 = h0*Wr2 + h1*We2 + b2, out1 = h1*Wr2 + h0*We2 + b2
    // Wr2/We2: [HID_D=16][OUT_D=4] row-major -> j-pairs contiguous.
    f4 o0, o1;
#pragma unroll
    for (int jj = 0; jj < 2; ++jj) {
        const f2 bb = *(const f2*)&b2[2 * jj];
        f2 s0 = bb, s1 = bb;
#pragma unroll
        for (int k = 0; k < 16; ++k) {
            const f2 wr = *(const f2*)&Wr2[k * 4 + 2 * jj];
            const f2 we = *(const f2*)&We2[k * 4 + 2 * jj];
            const f2 e0 = bc(h0s[k]);
            const f2 e1 = bc(h1s[k]);
            s0 = __builtin_elementwise_fma(e0, wr, s0);
            s0 = __builtin_elementwise_fma(e1, we, s0);
            s1 = __builtin_elementwise_fma(e1, wr, s1);
            s1 = __builtin_elementwise_fma(e0, we, s1);
        }
        o0[2 * jj] = s0.x; o0[2 * jj + 1] = s0.y;
        o1[2 * jj] = s1.x; o1[2 * jj + 1] = s1.y;
    }

    // write-only stream -> nontemporal stores (32B contiguous per thread)
    __builtin_nontemporal_store(o0, &ov[2 * g]);
    __builtin_nontemporal_store(o1, &ov[2 * g + 1]);
}

extern "C" void kernel_launch(void* const* d_in, const int* in_sizes, int n_in,
                              void* d_out, int out_size, void* d_ws, size_t ws_size,
                              hipStream_t stream) {
    const float* x   = (const float*)d_in[0];
    // d_in[1] = edge_index — static topology, never read.
    const float* Wr1 = (const float*)d_in[2];
    const float* We1 = (const float*)d_in[3];
    const float* b1  = (const float*)d_in[4];
    const float* Wr2 = (const float*)d_in[5];
    const float* We2 = (const float*)d_in[6];
    const float* b2  = (const float*)d_in[7];

    const int nGraphs = in_sizes[0] / 8;   // N*IN_D / (2*4) = B

    const int block = 256;
    const int grid  = (nGraphs + block - 1) / block;   // 3907 blocks
    gnn2_kernel<<<grid, block, 0, stream>>>((const f4*)x, Wr1, We1, b1,
                                            Wr2, We2, b2, (f4*)d_out, nGraphs);
}